// Round 7
// baseline (4291.142 us; speedup 1.0000x reference)
//
#include <hip/hip_runtime.h>
#include <hip/hip_bf16.h>

#define B_  4
#define T_  2048
#define D_  2048
#define H_  16
#define DH_ 128

typedef __attribute__((ext_vector_type(4))) float f32x4;
typedef __attribute__((ext_vector_type(8))) short short8;
typedef __attribute__((ext_vector_type(4))) _Float16 half4;

__device__ __forceinline__ ushort f2bf(float f) {
    unsigned int u = __builtin_bit_cast(unsigned int, f);
    u += 0x7fffu + ((u >> 16) & 1u);   // RNE
    return (ushort)(u >> 16);
}
__device__ __forceinline__ ushort f2h(float f) {
    return (ushort)(__builtin_bit_cast(unsigned int, __builtin_amdgcn_cvt_pkrtz(f, f)) & 0xffffu);
}

// async global -> LDS, 16B per lane. LDS dst must be wave-uniform base + lane*16.
__device__ __forceinline__ void glds16(const void* g, void* l) {
    __builtin_amdgcn_global_load_lds(
        (const __attribute__((address_space(1))) unsigned int*)g,
        (__attribute__((address_space(3))) unsigned int*)l, 16, 0, 0);
}

// ---------------------------------------------------------------- cast x -> bf16
__global__ void cast_f32_bf16(const float* __restrict__ x, ushort* __restrict__ xb, int n) {
    int i = (blockIdx.x * 256 + threadIdx.x) * 4;
    if (i < n) {
        float4 v = *(const float4*)(x + i);
        ushort4 o;
        o.x = f2bf(v.x); o.y = f2bf(v.y); o.z = f2bf(v.z); o.w = f2bf(v.w);
        *(ushort4*)(xb + i) = o;
    }
}

// ------------------------------------------------- 4x fused: W [k][n] fp32 -> Wt [n][k] bf16
__global__ void transpose_cast4(
    const float* __restrict__ W0, const float* __restrict__ W1,
    const float* __restrict__ W2, const float* __restrict__ W3,
    ushort* __restrict__ T0, ushort* __restrict__ T1,
    ushort* __restrict__ T2, ushort* __restrict__ T3)
{
    const int z = blockIdx.z;
    const float* W = (z == 0) ? W0 : (z == 1) ? W1 : (z == 2) ? W2 : W3;
    ushort* Wt     = (z == 0) ? T0 : (z == 1) ? T1 : (z == 2) ? T2 : T3;
    __shared__ float tile[32][33];
    int tx = threadIdx.x, ty = threadIdx.y;           // 32 x 8
    int n0 = blockIdx.x * 32, k0 = blockIdx.y * 32;
#pragma unroll
    for (int i = 0; i < 4; i++)
        tile[ty + i * 8][tx] = W[(size_t)(k0 + ty + i * 8) * D_ + n0 + tx];
    __syncthreads();
#pragma unroll
    for (int i = 0; i < 4; i++)
        Wt[(size_t)(n0 + ty + i * 8) * D_ + k0 + tx] = f2bf(tile[tx][ty + i * 8]);
}

// ---------------------------------------------------------------- merged QKV GEMM (128^2, proven)
// R6: y0 row-offset param so the launch can split into 2 dispatches of 1536 blocks
// (2 exact occupancy rounds of 768 each at 3/CU) -> attn becomes the top rocprof dispatch.
__global__ __launch_bounds__(256, 3) void gemm_qkv(
    const ushort* __restrict__ A,
    const ushort* __restrict__ Wq, const ushort* __restrict__ Wk, const ushort* __restrict__ Wv,
    const float* __restrict__ bq, const float* __restrict__ bk, const float* __restrict__ bv,
    ushort* __restrict__ Qb, ushort* __restrict__ Kb, ushort* __restrict__ Vtb,
    float qscale, int y0)
{
    extern __shared__ char smem[];
    uint4* sA = (uint4*)smem;              // [128 rows][4 chunks], slot c holds chunk c^sw(row)
    uint4* sB = (uint4*)(smem + 8192);

    const int tid  = threadIdx.x;
    const int sel  = blockIdx.x >> 4;           // 0=Q 1=K 2=V
    const int row0 = (blockIdx.y + y0) * 128, col0 = (blockIdx.x & 15) * 128;
    const ushort* Bt = (sel == 0) ? Wq : (sel == 1) ? Wk : Wv;
    const float* bias = (sel == 0) ? bq : (sel == 1) ? bk : bv;
    const float oscale = (sel == 0) ? qscale : 1.0f;
    const int K = D_, N = D_;

    const int mA = tid >> 2, g = tid & 3;
    const int gc = g ^ ((mA >> 2) & 3);
    const ushort* pa0 = A  + (size_t)(row0 + mA) * K + gc * 8;
    const ushort* pb0 = Bt + (size_t)(col0 + mA) * K + gc * 8;

    const int lane = tid & 63, w = tid >> 6;
    const int l15 = lane & 15, quad = lane >> 4;
    const int wm = w & 1, wn = w >> 1;
    const int csel = quad ^ ((l15 >> 2) & 3);
    int aoff[4], boff[4];
#pragma unroll
    for (int mt = 0; mt < 4; mt++) aoff[mt] = (wm * 64 + mt * 16 + l15) * 4 + csel;
#pragma unroll
    for (int nt = 0; nt < 4; nt++) boff[nt] = (wn * 64 + nt * 16 + l15) * 4 + csel;

    f32x4 acc[4][4] = {};

    const int kIter = K >> 5;
    for (int kt = 0; kt < kIter; ++kt) {
        if (kt) __syncthreads();
        glds16(pa0 + kt * 32,                     sA + tid);
        glds16(pa0 + kt * 32 + (size_t)64 * K,    sA + tid + 256);
        glds16(pb0 + kt * 32,                     sB + tid);
        glds16(pb0 + kt * 32 + (size_t)64 * K,    sB + tid + 256);
        __syncthreads();
        short8 af[4], bfr[4];
#pragma unroll
        for (int mt = 0; mt < 4; mt++) af[mt]  = __builtin_bit_cast(short8, sA[aoff[mt]]);
#pragma unroll
        for (int nt = 0; nt < 4; nt++) bfr[nt] = __builtin_bit_cast(short8, sB[boff[nt]]);
#pragma unroll
        for (int mt = 0; mt < 4; mt++)
#pragma unroll
            for (int nt = 0; nt < 4; nt++)
                acc[mt][nt] = __builtin_amdgcn_mfma_f32_16x16x32_bf16(af[mt], bfr[nt], acc[mt][nt], 0, 0, 0);
    }

    if (sel < 2) {
        ushort* Cout = (sel == 0) ? Qb : Kb;
#pragma unroll
        for (int nt = 0; nt < 4; nt++) {
            int col = col0 + wn * 64 + nt * 16 + l15;
            float bb = bias[col];
#pragma unroll
            for (int mt = 0; mt < 4; mt++) {
                int rowb = row0 + wm * 64 + mt * 16 + quad * 4;
#pragma unroll
                for (int r = 0; r < 4; ++r)
                    Cout[(size_t)(rowb + r) * N + col] = f2bf((acc[mt][nt][r] + bb) * oscale);
            }
        }
    } else {
        // V path: transpose 128x128 tile through LDS, emit f16 [B,H,DH,T]
        __syncthreads();
        ushort* tr = (ushort*)smem;        // [128 dh][136]
#pragma unroll
        for (int nt = 0; nt < 4; nt++) {
            int cl = wn * 64 + nt * 16 + l15;
            float bb = bias[col0 + cl];
#pragma unroll
            for (int mt = 0; mt < 4; mt++) {
                int rl = wm * 64 + mt * 16 + quad * 4;
#pragma unroll
                for (int r = 0; r < 4; ++r)
                    tr[cl * 136 + rl + r] = f2h(acc[mt][nt][r] + bb);
            }
        }
        __syncthreads();
        int b = row0 >> 11, t0 = row0 & (T_ - 1), h = col0 >> 7;
        for (int idx = tid; idx < 2048; idx += 256) {
            int dh = idx >> 4, c = idx & 15;
            uint4 v = *(const uint4*)(tr + dh * 136 + c * 8);
            *(uint4*)(Vtb + (size_t)((b * H_ + h) * DH_ + dh) * T_ + t0 + c * 8) = v;
        }
    }
}

// ---------------------------------------------------------------- O-projection GEMM (f32 out)
// R6: launch_bounds(256,4): 60 arch + 64 AGPR = 124 <= 128-reg cap -> 4 blocks/CU,
// 1024 blocks = exactly 1 occupancy round (was 2 quantized rounds at 67% util at 3/CU).
__global__ __launch_bounds__(256, 4) void gemm_bt_f32(
    const ushort* __restrict__ A, const ushort* __restrict__ Bt,
    const float* __restrict__ bias, float* __restrict__ Cout,
    int M, int N, int K)
{
    extern __shared__ char smem[];
    uint4* sA = (uint4*)smem;
    uint4* sB = (uint4*)(smem + 8192);

    const int tid  = threadIdx.x;
    const int row0 = blockIdx.y * 128, col0 = blockIdx.x * 128;

    const int mA = tid >> 2, g = tid & 3;
    const int gc = g ^ ((mA >> 2) & 3);
    const ushort* pa0 = A  + (size_t)(row0 + mA) * K + gc * 8;
    const ushort* pb0 = Bt + (size_t)(col0 + mA) * K + gc * 8;

    const int lane = tid & 63, w = tid >> 6;
    const int l15 = lane & 15, quad = lane >> 4;
    const int wm = w & 1, wn = w >> 1;
    const int csel = quad ^ ((l15 >> 2) & 3);
    int aoff[4], boff[4];
#pragma unroll
    for (int mt = 0; mt < 4; mt++) aoff[mt] = (wm * 64 + mt * 16 + l15) * 4 + csel;
#pragma unroll
    for (int nt = 0; nt < 4; nt++) boff[nt] = (wn * 64 + nt * 16 + l15) * 4 + csel;

    f32x4 acc[4][4] = {};

    const int kIter = K >> 5;
    for (int kt = 0; kt < kIter; ++kt) {
        if (kt) __syncthreads();
        glds16(pa0 + kt * 32,                     sA + tid);
        glds16(pa0 + kt * 32 + (size_t)64 * K,    sA + tid + 256);
        glds16(pb0 + kt * 32,                     sB + tid);
        glds16(pb0 + kt * 32 + (size_t)64 * K,    sB + tid + 256);
        __syncthreads();
        short8 af[4], bfr[4];
#pragma unroll
        for (int mt = 0; mt < 4; mt++) af[mt]  = __builtin_bit_cast(short8, sA[aoff[mt]]);
#pragma unroll
        for (int nt = 0; nt < 4; nt++) bfr[nt] = __builtin_bit_cast(short8, sB[boff[nt]]);
#pragma unroll
        for (int mt = 0; mt < 4; mt++)
#pragma unroll
            for (int nt = 0; nt < 4; nt++)
                acc[mt][nt] = __builtin_amdgcn_mfma_f32_16x16x32_bf16(af[mt], bfr[nt], acc[mt][nt], 0, 0, 0);
    }

#pragma unroll
    for (int nt = 0; nt < 4; nt++) {
        int col = col0 + wn * 64 + nt * 16 + l15;
        float bb = bias[col];
#pragma unroll
        for (int mt = 0; mt < 4; mt++) {
            int rowb = row0 + wm * 64 + mt * 16 + quad * 4;
#pragma unroll
            for (int r = 0; r < 4; ++r)
                Cout[(size_t)(rowb + r) * N + col] = acc[mt][nt][r] + bb;
        }
    }
}

// ---------------------------------------------------------------- flash attention (S^T / O^T form)
// Q (pre-scaled by 1/sqrt(DH)*log2e), K: [B,T,D] bf16 ; Vt: [B,H,DH,T] f16 ; O: [B,T,D] bf16
// R6: 128-row q-block, 4 waves x 32 q-rows (two 16-col groups qh0/qh1 per wave).
// Per staged K/V tile, every K/V fragment load feeds TWO MFMAs (qh0,qh1) -> 2x compute
// per barrier; stagings per 128 q-rows drop 24.5 -> avg 17 (nT = 2*qi+2). Causal per
// wave: qv = q_low - s0; skip tile if qv<0; per qh stMax = min(4,(qv+16*qh)/16+1);
// fine-mask only st == stMax-1 (when qv+16*qh < 64). Long blocks dispatched first.
// K single-buffered + prefetch after QK barrier; V double-buffered. 48 KiB LDS.
#define SMX_(ST, SM, MR, LR, ACC, PB) do {                                                 \
    float rmax_ = -INFINITY;                                                               \
    _Pragma("unroll") for (int st = 0; st < 4; ++st)                                       \
      if (st < (SM))                                                                       \
        _Pragma("unroll") for (int r = 0; r < 4; ++r) rmax_ = fmaxf(rmax_, ST[st][r]);     \
    rmax_ = fmaxf(rmax_, __shfl_xor(rmax_, 16));                                           \
    rmax_ = fmaxf(rmax_, __shfl_xor(rmax_, 32));                                           \
    if (!__all(rmax_ <= (MR) + 8.0f)) {                                                    \
      float mnew_ = fmaxf((MR), rmax_);                                                    \
      float al_ = __builtin_amdgcn_exp2f((MR) - mnew_);                                    \
      (MR) = mnew_; (LR) *= al_;                                                           \
      _Pragma("unroll") for (int nt = 0; nt < 8; ++nt)                                     \
        _Pragma("unroll") for (int r = 0; r < 4; ++r) ACC[nt][r] *= al_;                   \
    }                                                                                      \
    float ps_ = 0.f;                                                                       \
    _Pragma("unroll") for (int st = 0; st < 4; ++st)                                       \
      if (st < (SM)) {                                                                     \
        float p0_ = __builtin_amdgcn_exp2f(ST[st][0] - (MR));                              \
        float p1_ = __builtin_amdgcn_exp2f(ST[st][1] - (MR));                              \
        float p2_ = __builtin_amdgcn_exp2f(ST[st][2] - (MR));                              \
        float p3_ = __builtin_amdgcn_exp2f(ST[st][3] - (MR));                              \
        ps_ += (p0_ + p1_) + (p2_ + p3_);                                                  \
        uint2 u_;                                                                          \
        u_.x = __builtin_bit_cast(unsigned int, __builtin_amdgcn_cvt_pkrtz(p0_, p1_));     \
        u_.y = __builtin_bit_cast(unsigned int, __builtin_amdgcn_cvt_pkrtz(p2_, p3_));     \
        PB[st] = __builtin_bit_cast(half4, u_);                                            \
      }                                                                                    \
    ps_ += __shfl_xor(ps_, 16);                                                            \
    ps_ += __shfl_xor(ps_, 32);                                                            \
    (LR) += ps_;                                                                           \
  } while (0)

__global__ __launch_bounds__(256, 2) void attn_kernel(
    const ushort* __restrict__ Q, const ushort* __restrict__ K,
    const ushort* __restrict__ Vt, ushort* __restrict__ O)
{
    __shared__ __align__(16) char smem[49152];
    uint4*  kS = (uint4*)smem;                 // [64 s][16 chunks], chunk-swizzled (16 KiB)
    ushort* vS = (ushort*)(smem + 16384);      // 2 x [128 dh][8 slot16], slot ^ (dh&7)

    const int tid = threadIdx.x;
    const int bid = blockIdx.x;
    const int slot = bid >> 3;
    const int g = (bid & 7) + 8 * (slot >> 4);   // all 16 q-blocks of head g on xcd g%8
    const int qi = 15 - (slot & 15);             // long blocks (high qi) dispatch first
    const int b = g >> 4, h = g & 15;

    const int lane = tid & 63, w = tid >> 6, l15 = lane & 15, quad = lane >> 4;

    const int krow = tid >> 4;                       // 0..15
    const int kchunk = (tid & 15) ^ (krow & 7);
    const ushort* kg = K + ((size_t)(b * T_) + krow) * D_ + h * DH_ + kchunk * 8;

    const int vdh = tid >> 3;                        // 0..31
    const int vslot = (tid & 7) ^ (vdh & 7);
    const ushort* vg = Vt + ((size_t)((b * H_ + h) * DH_) + vdh) * T_ + vslot * 8;
    char* vdst = smem + 16384 + tid * 16;

    const int q0 = qi * 128;
    const int qlow = q0 + w * 32;                // wave's first q row
    const int nT = 2 * qi + 2;

    // Q B-fragments: qh0 = rows qlow..+15, qh1 = rows qlow+16..+31
    short8 aq0[4], aq1[4];
    {
        const ushort* qp0 = Q + ((size_t)(b * T_) + qlow + l15) * D_ + h * DH_ + quad * 8;
        const ushort* qp1 = qp0 + (size_t)16 * D_;
#pragma unroll
        for (int ks = 0; ks < 4; ++ks) {
            aq0[ks] = __builtin_bit_cast(short8, *(const uint4*)(qp0 + ks * 32));
            aq1[ks] = __builtin_bit_cast(short8, *(const uint4*)(qp1 + ks * 32));
        }
    }

    f32x4 acc0[8] = {}, acc1[8] = {};            // O^T[dh=nt*16+quad*4+r][q = qh*16+l15]
    float m0 = -INFINITY, l0 = 0.f;
    float m1 = -INFINITY, l1 = 0.f;

    // prologue: stage tile 0 (K -> kS, V -> vS buf0)
#pragma unroll
    for (int j = 0; j < 4; ++j) glds16(kg + (size_t)j * 16 * D_, kS + j * 256 + tid);
#pragma unroll
    for (int j = 0; j < 4; ++j) glds16(vg + (size_t)j * 32 * T_, vdst + j * 4096);

    for (int i = 0; i < nT; ++i) {
        const int s0 = i * 64;
        const int qv0 = qlow - s0;               // wave-uniform
        const int qv1 = qv0 + 16;
        const bool act = (qv0 >= 0);
        const int sm0 = act ? ((qv0 >= 48) ? 4 : ((qv0 >> 4) + 1)) : 0;
        const int sm1 = act ? ((qv1 >= 48) ? 4 : ((qv1 >> 4) + 1)) : 0;

        __syncthreads();                         // K(i)/V(i) landed (vmcnt0); prev PV done

        half4 pb0[4], pb1[4];
        if (act) {
            f32x4 sT0[4], sT1[4];
            sT0[0] = (f32x4)(0.f); sT0[1] = (f32x4)(0.f); sT0[2] = (f32x4)(0.f); sT0[3] = (f32x4)(0.f);
            sT1[0] = (f32x4)(0.f); sT1[1] = (f32x4)(0.f); sT1[2] = (f32x4)(0.f); sT1[3] = (f32x4)(0.f);
            __builtin_amdgcn_s_setprio(1);
#pragma unroll
            for (int st = 0; st < 4; ++st)
                if (st < sm1) {                  // sm1 >= sm0 always
#pragma unroll
                    for (int ks = 0; ks < 4; ++ks) {
                        int row_ = st * 16 + l15;
                        short8 ak_ = __builtin_bit_cast(short8,
                            kS[row_ * 16 + ((ks * 4 + quad) ^ (row_ & 7))]);
                        if (st < sm0)
                            sT0[st] = __builtin_amdgcn_mfma_f32_16x16x32_bf16(ak_, aq0[ks], sT0[st], 0, 0, 0);
                        sT1[st] = __builtin_amdgcn_mfma_f32_16x16x32_bf16(ak_, aq1[ks], sT1[st], 0, 0, 0);
                    }
                }
            __builtin_amdgcn_s_setprio(0);

            if (qv0 < 64) {                      // fine-mask st == sm0-1
#pragma unroll
                for (int st = 0; st < 4; ++st)
                    if (st == sm0 - 1) {
#pragma unroll
                        for (int r = 0; r < 4; ++r)
                            if (st * 16 + quad * 4 + r > qv0 + l15) sT0[st][r] = -INFINITY;
                    }
            }
            if (qv1 < 64) {
#pragma unroll
                for (int st = 0; st < 4; ++st)
                    if (st == sm1 - 1) {
#pragma unroll
                        for (int r = 0; r < 4; ++r)
                            if (st * 16 + quad * 4 + r > qv1 + l15) sT1[st][r] = -INFINITY;
                    }
            }

            SMX_(sT0, sm0, m0, l0, acc0, pb0);
            SMX_(sT1, sm1, m1, l1, acc1, pb1);
        }

        __syncthreads();                         // all waves done reading kS

        if (i + 1 < nT) {                        // prefetch tile i+1 under PV
            const ushort* kp = kg + (size_t)(s0 + 64) * D_;
#pragma unroll
            for (int j = 0; j < 4; ++j) glds16(kp + (size_t)j * 16 * D_, kS + j * 256 + tid);
            const ushort* vp = vg + s0 + 64;
            char* vd = vdst + (((i + 1) & 1) << 14);
#pragma unroll
            for (int j = 0; j < 4; ++j) glds16(vp + (size_t)j * 32 * T_, vd + j * 4096);
        }

        if (act) {
            const ushort* vb = vS + ((i & 1) << 13);
            __builtin_amdgcn_s_setprio(1);
#pragma unroll
            for (int st = 0; st < 4; ++st)
                if (st < sm1) {
                    const int s8_ = st * 4 + quad;
                    const int off_ = (((s8_ >> 1) ^ (l15 & 7)) << 3) + ((s8_ & 1) << 2);
#pragma unroll
                    for (int nt = 0; nt < 8; ++nt) {
                        int dh_ = nt * 16 + l15;
                        half4 vf_ = *(const half4*)(vb + dh_ * 64 + off_);
                        if (st < sm0)
                            acc0[nt] = __builtin_amdgcn_mfma_f32_16x16x16f16(vf_, pb0[st], acc0[nt], 0, 0, 0);
                        acc1[nt] = __builtin_amdgcn_mfma_f32_16x16x16f16(vf_, pb1[st], acc1[nt], 0, 0, 0);
                    }
                }
            __builtin_amdgcn_s_setprio(0);
        }
    }

    // epilogue: transpose O^T -> O via wave-private LDS, write bf16 (32 rows per wave)
    __syncthreads();                              // all PV reads of vS done (eT overlaps kS/vS)
    ushort* eT = (ushort*)smem + w * 4352;        // [32 q][136 dh-pad]
    {
        float inv0 = 1.0f / l0, inv1 = 1.0f / l1;
#pragma unroll
        for (int nt = 0; nt < 8; ++nt) {
            int dh_ = nt * 16 + quad * 4;
#pragma unroll
            for (int r = 0; r < 4; ++r) {
                eT[l15 * 136 + dh_ + r]        = f2bf(acc0[nt][r] * inv0);
                eT[(16 + l15) * 136 + dh_ + r] = f2bf(acc1[nt][r] * inv1);
            }
        }
        for (int idx = lane; idx < 512; idx += 64) {
            int row_ = idx >> 4, c_ = idx & 15;
            uint4 v_ = *(const uint4*)(eT + row_ * 136 + c_ * 8);
            *(uint4*)(O + ((size_t)(b * T_) + q0 + w * 32 + row_) * D_ + h * DH_ + c_ * 8) = v_;
        }
    }
}

extern "C" void kernel_launch(void* const* d_in, const int* in_sizes, int n_in,
                              void* d_out, int out_size, void* d_ws, size_t ws_size,
                              hipStream_t stream) {
    const float* x  = (const float*)d_in[0];
    const float* Wq = (const float*)d_in[1];
    const float* bq = (const float*)d_in[2];
    const float* Wk = (const float*)d_in[3];
    const float* bk = (const float*)d_in[4];
    const float* Wv = (const float*)d_in[5];
    const float* bv = (const float*)d_in[6];
    const float* Wo = (const float*)d_in[7];
    const float* bo = (const float*)d_in[8];

    char* ws = (char*)d_ws;
    const size_t MB = 1u << 20;
    ushort* xb  = (ushort*)(ws);
    ushort* Wqt = (ushort*)(ws + 32 * MB);
    ushort* Wkt = (ushort*)(ws + 40 * MB);
    ushort* Wvt = (ushort*)(ws + 48 * MB);
    ushort* Wot = (ushort*)(ws + 56 * MB);
    ushort* Qb  = (ushort*)(ws + 64 * MB);
    ushort* Kb  = (ushort*)(ws + 96 * MB);
    ushort* Vtb = (ushort*)(ws + 128 * MB);
    ushort* Ob  = (ushort*)(ws + 160 * MB);

    const int M = B_ * T_;   // 8192
    const float qscale = (float)(0.08838834764831845 * 1.4426950408889634); // 1/sqrt(DH) * log2(e)

    cast_f32_bf16<<<(M * D_) / 1024, 256, 0, stream>>>(x, xb, M * D_);
    dim3 tb(32, 8), tg(D_ / 32, D_ / 32, 4);
    transpose_cast4<<<tg, tb, 0, stream>>>(Wq, Wk, Wv, Wo, Wqt, Wkt, Wvt, Wot);

    gemm_qkv<<<dim3(48, 32), 256, 34816, stream>>>(
        xb, Wqt, Wkt, Wvt, bq, bk, bv, Qb, Kb, Vtb, qscale, 0);
    gemm_qkv<<<dim3(48, 32), 256, 34816, stream>>>(
        xb, Wqt, Wkt, Wvt, bq, bk, bv, Qb, Kb, Vtb, qscale, 32);

    attn_kernel<<<dim3(1024), 256, 0, stream>>>(Qb, Kb, Vtb, Ob);

    gemm_bt_f32<<<dim3(D_ / 128, M / 128), 256, 16384, stream>>>(
        Ob, Wot, bo, (float*)d_out, M, D_, D_);
}

// Round 8
// 628.947 us; speedup vs baseline: 6.8227x; 6.8227x over previous
//
#include <hip/hip_runtime.h>
#include <hip/hip_bf16.h>

#define B_  4
#define T_  2048
#define D_  2048
#define H_  16
#define DH_ 128

typedef __attribute__((ext_vector_type(4))) float f32x4;
typedef __attribute__((ext_vector_type(8))) short short8;
typedef __attribute__((ext_vector_type(4))) _Float16 half4;

__device__ __forceinline__ ushort f2bf(float f) {
    unsigned int u = __builtin_bit_cast(unsigned int, f);
    u += 0x7fffu + ((u >> 16) & 1u);   // RNE
    return (ushort)(u >> 16);
}
__device__ __forceinline__ ushort f2h(float f) {
    return (ushort)(__builtin_bit_cast(unsigned int, __builtin_amdgcn_cvt_pkrtz(f, f)) & 0xffffu);
}

// async global -> LDS, 16B per lane. LDS dst must be wave-uniform base + lane*16.
__device__ __forceinline__ void glds16(const void* g, void* l) {
    __builtin_amdgcn_global_load_lds(
        (const __attribute__((address_space(1))) unsigned int*)g,
        (__attribute__((address_space(3))) unsigned int*)l, 16, 0, 0);
}

// ---------------------------------------------------------------- cast x -> bf16
__global__ void cast_f32_bf16(const float* __restrict__ x, ushort* __restrict__ xb, int n) {
    int i = (blockIdx.x * 256 + threadIdx.x) * 4;
    if (i < n) {
        float4 v = *(const float4*)(x + i);
        ushort4 o;
        o.x = f2bf(v.x); o.y = f2bf(v.y); o.z = f2bf(v.z); o.w = f2bf(v.w);
        *(ushort4*)(xb + i) = o;
    }
}

// ------------------------------------------------- 4x fused: W [k][n] fp32 -> Wt [n][k] bf16
__global__ void transpose_cast4(
    const float* __restrict__ W0, const float* __restrict__ W1,
    const float* __restrict__ W2, const float* __restrict__ W3,
    ushort* __restrict__ T0, ushort* __restrict__ T1,
    ushort* __restrict__ T2, ushort* __restrict__ T3)
{
    const int z = blockIdx.z;
    const float* W = (z == 0) ? W0 : (z == 1) ? W1 : (z == 2) ? W2 : W3;
    ushort* Wt     = (z == 0) ? T0 : (z == 1) ? T1 : (z == 2) ? T2 : T3;
    __shared__ float tile[32][33];
    int tx = threadIdx.x, ty = threadIdx.y;           // 32 x 8
    int n0 = blockIdx.x * 32, k0 = blockIdx.y * 32;
#pragma unroll
    for (int i = 0; i < 4; i++)
        tile[ty + i * 8][tx] = W[(size_t)(k0 + ty + i * 8) * D_ + n0 + tx];
    __syncthreads();
#pragma unroll
    for (int i = 0; i < 4; i++)
        Wt[(size_t)(n0 + ty + i * 8) * D_ + k0 + tx] = f2bf(tile[tx][ty + i * 8]);
}

// ---------------------------------------------------------------- merged QKV GEMM (128^2, proven)
// y0 row-offset: launched as 2 dispatches of 1536 blocks (2 exact occupancy rounds of
// 768 at 3/CU) -> attn becomes the top rocprof dispatch (instrumentation, zero cost).
__global__ __launch_bounds__(256, 3) void gemm_qkv(
    const ushort* __restrict__ A,
    const ushort* __restrict__ Wq, const ushort* __restrict__ Wk, const ushort* __restrict__ Wv,
    const float* __restrict__ bq, const float* __restrict__ bk, const float* __restrict__ bv,
    ushort* __restrict__ Qb, ushort* __restrict__ Kb, ushort* __restrict__ Vtb,
    float qscale, int y0)
{
    extern __shared__ char smem[];
    uint4* sA = (uint4*)smem;              // [128 rows][4 chunks], slot c holds chunk c^sw(row)
    uint4* sB = (uint4*)(smem + 8192);

    const int tid  = threadIdx.x;
    const int sel  = blockIdx.x >> 4;           // 0=Q 1=K 2=V
    const int row0 = (blockIdx.y + y0) * 128, col0 = (blockIdx.x & 15) * 128;
    const ushort* Bt = (sel == 0) ? Wq : (sel == 1) ? Wk : Wv;
    const float* bias = (sel == 0) ? bq : (sel == 1) ? bk : bv;
    const float oscale = (sel == 0) ? qscale : 1.0f;
    const int K = D_, N = D_;

    const int mA = tid >> 2, g = tid & 3;
    const int gc = g ^ ((mA >> 2) & 3);
    const ushort* pa0 = A  + (size_t)(row0 + mA) * K + gc * 8;
    const ushort* pb0 = Bt + (size_t)(col0 + mA) * K + gc * 8;

    const int lane = tid & 63, w = tid >> 6;
    const int l15 = lane & 15, quad = lane >> 4;
    const int wm = w & 1, wn = w >> 1;
    const int csel = quad ^ ((l15 >> 2) & 3);
    int aoff[4], boff[4];
#pragma unroll
    for (int mt = 0; mt < 4; mt++) aoff[mt] = (wm * 64 + mt * 16 + l15) * 4 + csel;
#pragma unroll
    for (int nt = 0; nt < 4; nt++) boff[nt] = (wn * 64 + nt * 16 + l15) * 4 + csel;

    f32x4 acc[4][4] = {};

    const int kIter = K >> 5;
    for (int kt = 0; kt < kIter; ++kt) {
        if (kt) __syncthreads();
        glds16(pa0 + kt * 32,                     sA + tid);
        glds16(pa0 + kt * 32 + (size_t)64 * K,    sA + tid + 256);
        glds16(pb0 + kt * 32,                     sB + tid);
        glds16(pb0 + kt * 32 + (size_t)64 * K,    sB + tid + 256);
        __syncthreads();
        short8 af[4], bfr[4];
#pragma unroll
        for (int mt = 0; mt < 4; mt++) af[mt]  = __builtin_bit_cast(short8, sA[aoff[mt]]);
#pragma unroll
        for (int nt = 0; nt < 4; nt++) bfr[nt] = __builtin_bit_cast(short8, sB[boff[nt]]);
#pragma unroll
        for (int mt = 0; mt < 4; mt++)
#pragma unroll
            for (int nt = 0; nt < 4; nt++)
                acc[mt][nt] = __builtin_amdgcn_mfma_f32_16x16x32_bf16(af[mt], bfr[nt], acc[mt][nt], 0, 0, 0);
    }

    if (sel < 2) {
        ushort* Cout = (sel == 0) ? Qb : Kb;
#pragma unroll
        for (int nt = 0; nt < 4; nt++) {
            int col = col0 + wn * 64 + nt * 16 + l15;
            float bb = bias[col];
#pragma unroll
            for (int mt = 0; mt < 4; mt++) {
                int rowb = row0 + wm * 64 + mt * 16 + quad * 4;
#pragma unroll
                for (int r = 0; r < 4; ++r)
                    Cout[(size_t)(rowb + r) * N + col] = f2bf((acc[mt][nt][r] + bb) * oscale);
            }
        }
    } else {
        // V path: transpose 128x128 tile through LDS, emit f16 [B,H,DH,T]
        __syncthreads();
        ushort* tr = (ushort*)smem;        // [128 dh][136]
#pragma unroll
        for (int nt = 0; nt < 4; nt++) {
            int cl = wn * 64 + nt * 16 + l15;
            float bb = bias[col0 + cl];
#pragma unroll
            for (int mt = 0; mt < 4; mt++) {
                int rl = wm * 64 + mt * 16 + quad * 4;
#pragma unroll
                for (int r = 0; r < 4; ++r)
                    tr[cl * 136 + rl + r] = f2h(acc[mt][nt][r] + bb);
            }
        }
        __syncthreads();
        int b = row0 >> 11, t0 = row0 & (T_ - 1), h = col0 >> 7;
        for (int idx = tid; idx < 2048; idx += 256) {
            int dh = idx >> 4, c = idx & 15;
            uint4 v = *(const uint4*)(tr + dh * 136 + c * 8);
            *(uint4*)(Vtb + (size_t)((b * H_ + h) * DH_ + dh) * T_ + t0 + c * 8) = v;
        }
    }
}

// ---------------------------------------------------------------- O-projection GEMM (f32 out)
// launch_bounds(256,4): 60 arch + 64 AGPR = 124 <= 128-reg cap -> 4 blocks/CU,
// 1024 blocks = exactly 1 occupancy round (was 2 quantized rounds at 67% util at 3/CU).
__global__ __launch_bounds__(256, 4) void gemm_bt_f32(
    const ushort* __restrict__ A, const ushort* __restrict__ Bt,
    const float* __restrict__ bias, float* __restrict__ Cout,
    int M, int N, int K)
{
    extern __shared__ char smem[];
    uint4* sA = (uint4*)smem;
    uint4* sB = (uint4*)(smem + 8192);

    const int tid  = threadIdx.x;
    const int row0 = blockIdx.y * 128, col0 = blockIdx.x * 128;

    const int mA = tid >> 2, g = tid & 3;
    const int gc = g ^ ((mA >> 2) & 3);
    const ushort* pa0 = A  + (size_t)(row0 + mA) * K + gc * 8;
    const ushort* pb0 = Bt + (size_t)(col0 + mA) * K + gc * 8;

    const int lane = tid & 63, w = tid >> 6;
    const int l15 = lane & 15, quad = lane >> 4;
    const int wm = w & 1, wn = w >> 1;
    const int csel = quad ^ ((l15 >> 2) & 3);
    int aoff[4], boff[4];
#pragma unroll
    for (int mt = 0; mt < 4; mt++) aoff[mt] = (wm * 64 + mt * 16 + l15) * 4 + csel;
#pragma unroll
    for (int nt = 0; nt < 4; nt++) boff[nt] = (wn * 64 + nt * 16 + l15) * 4 + csel;

    f32x4 acc[4][4] = {};

    const int kIter = K >> 5;
    for (int kt = 0; kt < kIter; ++kt) {
        if (kt) __syncthreads();
        glds16(pa0 + kt * 32,                     sA + tid);
        glds16(pa0 + kt * 32 + (size_t)64 * K,    sA + tid + 256);
        glds16(pb0 + kt * 32,                     sB + tid);
        glds16(pb0 + kt * 32 + (size_t)64 * K,    sB + tid + 256);
        __syncthreads();
        short8 af[4], bfr[4];
#pragma unroll
        for (int mt = 0; mt < 4; mt++) af[mt]  = __builtin_bit_cast(short8, sA[aoff[mt]]);
#pragma unroll
        for (int nt = 0; nt < 4; nt++) bfr[nt] = __builtin_bit_cast(short8, sB[boff[nt]]);
#pragma unroll
        for (int mt = 0; mt < 4; mt++)
#pragma unroll
            for (int nt = 0; nt < 4; nt++)
                acc[mt][nt] = __builtin_amdgcn_mfma_f32_16x16x32_bf16(af[mt], bfr[nt], acc[mt][nt], 0, 0, 0);
    }

#pragma unroll
    for (int nt = 0; nt < 4; nt++) {
        int col = col0 + wn * 64 + nt * 16 + l15;
        float bb = bias[col];
#pragma unroll
        for (int mt = 0; mt < 4; mt++) {
            int rowb = row0 + wm * 64 + mt * 16 + quad * 4;
#pragma unroll
            for (int r = 0; r < 4; ++r)
                Cout[(size_t)(rowb + r) * N + col] = acc[mt][nt][r] + bb;
        }
    }
}

// ---------------------------------------------------------------- flash attention (S^T / O^T form)
// R7: verbatim revert to the R0-proven kernel (616.7us session): two-pass (qx, 31-qx),
// 32 KiB LDS, (256,5), K via glds16, V via reg->swizzled-LDS, no prefetch, no defer-max.
__global__ __launch_bounds__(256, 5) void attn_kernel(
    const ushort* __restrict__ Q, const ushort* __restrict__ K,
    const ushort* __restrict__ Vt, ushort* __restrict__ O)
{
    __shared__ __align__(16) char smem[32768];
    uint4*  kS = (uint4*)smem;                 // [64 s][16 chunks], chunk-swizzled
    ushort* vS = (ushort*)(smem + 16384);      // [128 dh][16 slots x 4 halfs], slot ^ (dh&15)

    const int tid = threadIdx.x;
    const int bid = blockIdx.x;
    const int slot = bid >> 3;
    const int g = (bid & 7) + 8 * (slot >> 4);
    const int qx = slot & 15;
    const int b = g >> 4, h = g & 15;

    const int lane = tid & 63, w = tid >> 6, l15 = lane & 15, quad = lane >> 4;

    const int krow = tid >> 4;                       // 0..15
    const int kchunk = (tid & 15) ^ (krow & 7);
    const ushort* kg = K + ((size_t)(b * T_) + krow) * D_ + h * DH_ + kchunk * 8;

    const int vrow = tid >> 3, vc = tid & 7;         // vrow 0..31, chunk 0..7 (8 halfs)
    const ushort* vg = Vt + ((size_t)((b * H_ + h) * DH_) + vrow) * T_ + vc * 8;
    const int vs0 = ((2 * vc    ) ^ (vrow & 15)) * 4;
    const int vs1 = ((2 * vc + 1) ^ (vrow & 15)) * 4;

    const int qts[2] = { qx, 31 - qx };

    for (int e = 0; e < 2; ++e) {
        const int qt = qts[e], q0 = qt * 64;
        const int qbase = q0 + w * 16;               // wave's first q

        short8 aq[4];
        {
            const ushort* qp = Q + ((size_t)(b * T_) + qbase + l15) * D_ + h * DH_ + quad * 8;
#pragma unroll
            for (int ks = 0; ks < 4; ++ks)
                aq[ks] = __builtin_bit_cast(short8, *(const uint4*)(qp + ks * 32));
        }

        f32x4 accO[8] = {};                          // O^T[dh=nt*16+quad*4+r][q=l15]
        float mrow = -INFINITY, lrow = 0.f;

        auto tile = [&](int s0, int stMax, bool diag) {
            __syncthreads();                          // prior tile's readers done
            const ushort* kp = kg + (size_t)s0 * D_;
#pragma unroll
            for (int j = 0; j < 4; ++j) glds16(kp + (size_t)j * 16 * D_, kS + j * 256 + tid);
            const ushort* vp = vg + s0;
            uint4 vv[4];
#pragma unroll
            for (int j = 0; j < 4; ++j) vv[j] = *(const uint4*)(vp + (size_t)j * 32 * T_);
#pragma unroll
            for (int j = 0; j < 4; ++j) {
                ushort* dst = vS + (j * 32 + vrow) * 64;
                *(uint2*)(dst + vs0) = make_uint2(vv[j].x, vv[j].y);
                *(uint2*)(dst + vs1) = make_uint2(vv[j].z, vv[j].w);
            }
            __syncthreads();                          // tile ready

            f32x4 sT[4] = {};
#pragma unroll
            for (int ks = 0; ks < 4; ++ks)
#pragma unroll
                for (int st = 0; st < 4; ++st)
                    if (st < stMax) {
                        int row = st * 16 + l15;
                        short8 ak = __builtin_bit_cast(short8, kS[row * 16 + ((ks * 4 + quad) ^ (row & 7))]);
                        sT[st] = __builtin_amdgcn_mfma_f32_16x16x32_bf16(ak, aq[ks], sT[st], 0, 0, 0);
                    }

            if (diag) {
                const int q = qbase + l15;
                const int st = stMax - 1;
#pragma unroll
                for (int r = 0; r < 4; ++r)
                    if (s0 + st * 16 + quad * 4 + r > q) sT[st][r] = -INFINITY;
            }

            float rmax = -INFINITY;
#pragma unroll
            for (int st = 0; st < 4; ++st)
                if (st < stMax)
#pragma unroll
                    for (int r = 0; r < 4; ++r) rmax = fmaxf(rmax, sT[st][r]);
            rmax = fmaxf(rmax, __shfl_xor(rmax, 16));
            rmax = fmaxf(rmax, __shfl_xor(rmax, 32));
            float mnew  = fmaxf(mrow, rmax);
            float alpha = __builtin_amdgcn_exp2f(mrow - mnew);
            mrow = mnew;

            float psum = 0.f;
            half4 pb[4];
#pragma unroll
            for (int st = 0; st < 4; ++st)
                if (st < stMax) {
                    float p0 = __builtin_amdgcn_exp2f(sT[st][0] - mnew);
                    float p1 = __builtin_amdgcn_exp2f(sT[st][1] - mnew);
                    float p2 = __builtin_amdgcn_exp2f(sT[st][2] - mnew);
                    float p3 = __builtin_amdgcn_exp2f(sT[st][3] - mnew);
                    psum += (p0 + p1) + (p2 + p3);
                    uint2 u;
                    u.x = __builtin_bit_cast(unsigned int, __builtin_amdgcn_cvt_pkrtz(p0, p1));
                    u.y = __builtin_bit_cast(unsigned int, __builtin_amdgcn_cvt_pkrtz(p2, p3));
                    pb[st] = __builtin_bit_cast(half4, u);
                }
            psum += __shfl_xor(psum, 16);
            psum += __shfl_xor(psum, 32);
            lrow = lrow * alpha + psum;
#pragma unroll
            for (int nt = 0; nt < 8; ++nt)
#pragma unroll
                for (int r = 0; r < 4; ++r) accO[nt][r] *= alpha;

#pragma unroll
            for (int st = 0; st < 4; ++st)
                if (st < stMax) {
#pragma unroll
                    for (int nt = 0; nt < 8; ++nt) {
                        int dh = nt * 16 + l15;
                        half4 vf = *(const half4*)(vS + dh * 64 + (((st * 4 + quad) ^ l15) * 4));
                        accO[nt] = __builtin_amdgcn_mfma_f32_16x16x16f16(vf, pb[st], accO[nt], 0, 0, 0);
                    }
                }
        };

        for (int it = 0; it < qt; ++it) tile(it * 64, 4, false);
        tile(qt * 64, w + 1, true);

        __syncthreads();                              // all waves done reading kS/vS
        ushort* eT = (ushort*)smem + w * 2176;        // [16 q][136 dh-pad]
        float inv = 1.0f / lrow;
#pragma unroll
        for (int nt = 0; nt < 8; ++nt) {
            int dh = nt * 16 + quad * 4;
#pragma unroll
            for (int r = 0; r < 4; ++r)
                eT[l15 * 136 + dh + r] = f2bf(accO[nt][r] * inv);
        }
        for (int idx = lane; idx < 256; idx += 64) {
            int row = idx >> 4, c = idx & 15;
            uint4 v = *(const uint4*)(eT + row * 136 + c * 8);
            *(uint4*)(O + ((size_t)(b * T_) + q0 + w * 16 + row) * D_ + h * DH_ + c * 8) = v;
        }
    }
}

extern "C" void kernel_launch(void* const* d_in, const int* in_sizes, int n_in,
                              void* d_out, int out_size, void* d_ws, size_t ws_size,
                              hipStream_t stream) {
    const float* x  = (const float*)d_in[0];
    const float* Wq = (const float*)d_in[1];
    const float* bq = (const float*)d_in[2];
    const float* Wk = (const float*)d_in[3];
    const float* bk = (const float*)d_in[4];
    const float* Wv = (const float*)d_in[5];
    const float* bv = (const float*)d_in[6];
    const float* Wo = (const float*)d_in[7];
    const float* bo = (const float*)d_in[8];

    char* ws = (char*)d_ws;
    const size_t MB = 1u << 20;
    ushort* xb  = (ushort*)(ws);
    ushort* Wqt = (ushort*)(ws + 32 * MB);
    ushort* Wkt = (ushort*)(ws + 40 * MB);
    ushort* Wvt = (ushort*)(ws + 48 * MB);
    ushort* Wot = (ushort*)(ws + 56 * MB);
    ushort* Qb  = (ushort*)(ws + 64 * MB);
    ushort* Kb  = (ushort*)(ws + 96 * MB);
    ushort* Vtb = (ushort*)(ws + 128 * MB);
    ushort* Ob  = (ushort*)(ws + 160 * MB);

    const int M = B_ * T_;   // 8192
    const float qscale = (float)(0.08838834764831845 * 1.4426950408889634); // 1/sqrt(DH) * log2(e)

    cast_f32_bf16<<<(M * D_) / 1024, 256, 0, stream>>>(x, xb, M * D_);
    dim3 tb(32, 8), tg(D_ / 32, D_ / 32, 4);
    transpose_cast4<<<tg, tb, 0, stream>>>(Wq, Wk, Wv, Wo, Wqt, Wkt, Wvt, Wot);

    gemm_qkv<<<dim3(48, 32), 256, 34816, stream>>>(
        xb, Wqt, Wkt, Wvt, bq, bk, bv, Qb, Kb, Vtb, qscale, 0);
    gemm_qkv<<<dim3(48, 32), 256, 34816, stream>>>(
        xb, Wqt, Wkt, Wvt, bq, bk, bv, Qb, Kb, Vtb, qscale, 32);

    attn_kernel<<<dim3(1024), 256, 0, stream>>>(Qb, Kb, Vtb, Ob);

    gemm_bt_f32<<<dim3(D_ / 128, M / 128), 256, 16384, stream>>>(
        Ob, Wot, bo, (float*)d_out, M, D_, D_);
}

// Round 9
// 607.388 us; speedup vs baseline: 7.0649x; 1.0355x over previous
//
#include <hip/hip_runtime.h>
#include <hip/hip_bf16.h>

#define B_  4
#define T_  2048
#define D_  2048
#define H_  16
#define DH_ 128

typedef __attribute__((ext_vector_type(4))) float f32x4;
typedef __attribute__((ext_vector_type(8))) short short8;
typedef __attribute__((ext_vector_type(4))) _Float16 half4;

__device__ __forceinline__ ushort f2bf(float f) {
    unsigned int u = __builtin_bit_cast(unsigned int, f);
    u += 0x7fffu + ((u >> 16) & 1u);   // RNE
    return (ushort)(u >> 16);
}
__device__ __forceinline__ ushort f2h(float f) {
    return (ushort)(__builtin_bit_cast(unsigned int, __builtin_amdgcn_cvt_pkrtz(f, f)) & 0xffffu);
}

// async global -> LDS, 16B per lane. LDS dst must be wave-uniform base + lane*16.
__device__ __forceinline__ void glds16(const void* g, void* l) {
    __builtin_amdgcn_global_load_lds(
        (const __attribute__((address_space(1))) unsigned int*)g,
        (__attribute__((address_space(3))) unsigned int*)l, 16, 0, 0);
}

// ------------------------------------------------- fused prep: cast x->bf16 + 4x W transpose
// grid (64,64,5): z<4 -> transpose W[z] [k][n] f32 -> Wt [n][k] bf16 ; z==4 -> cast plane
// (4096 blocks x 4096 elems = 16.7M = M*D exactly).
__global__ void prep_kernel(
    const float* __restrict__ x, ushort* __restrict__ xb,
    const float* __restrict__ W0, const float* __restrict__ W1,
    const float* __restrict__ W2, const float* __restrict__ W3,
    ushort* __restrict__ T0, ushort* __restrict__ T1,
    ushort* __restrict__ T2, ushort* __restrict__ T3)
{
    __shared__ float tile[32][33];
    const int z = blockIdx.z;
    int tx = threadIdx.x, ty = threadIdx.y;           // 32 x 8
    if (z == 4) {
        int blk = blockIdx.y * 64 + blockIdx.x;
        int tid = ty * 32 + tx;
        size_t base = (size_t)blk * 4096 + tid * 4;
#pragma unroll
        for (int k2 = 0; k2 < 4; ++k2) {
            float4 v = *(const float4*)(x + base + k2 * 1024);
            ushort4 o;
            o.x = f2bf(v.x); o.y = f2bf(v.y); o.z = f2bf(v.z); o.w = f2bf(v.w);
            *(ushort4*)(xb + base + k2 * 1024) = o;
        }
        return;
    }
    const float* W = (z == 0) ? W0 : (z == 1) ? W1 : (z == 2) ? W2 : W3;
    ushort* Wt     = (z == 0) ? T0 : (z == 1) ? T1 : (z == 2) ? T2 : T3;
    int n0 = blockIdx.x * 32, k0 = blockIdx.y * 32;
#pragma unroll
    for (int i = 0; i < 4; i++)
        tile[ty + i * 8][tx] = W[(size_t)(k0 + ty + i * 8) * D_ + n0 + tx];
    __syncthreads();
#pragma unroll
    for (int i = 0; i < 4; i++)
        Wt[(size_t)(n0 + ty + i * 8) * D_ + k0 + tx] = f2bf(tile[tx][ty + i * 8]);
}

// ---------------------------------------------------------------- merged QKV GEMM (128^2, proven)
__global__ __launch_bounds__(256, 3) void gemm_qkv(
    const ushort* __restrict__ A,
    const ushort* __restrict__ Wq, const ushort* __restrict__ Wk, const ushort* __restrict__ Wv,
    const float* __restrict__ bq, const float* __restrict__ bk, const float* __restrict__ bv,
    ushort* __restrict__ Qb, ushort* __restrict__ Kb, ushort* __restrict__ Vtb,
    float qscale)
{
    extern __shared__ char smem[];
    uint4* sA = (uint4*)smem;              // [128 rows][4 chunks], slot c holds chunk c^sw(row)
    uint4* sB = (uint4*)(smem + 8192);

    const int tid  = threadIdx.x;
    const int sel  = blockIdx.x >> 4;           // 0=Q 1=K 2=V
    const int row0 = blockIdx.y * 128, col0 = (blockIdx.x & 15) * 128;
    const ushort* Bt = (sel == 0) ? Wq : (sel == 1) ? Wk : Wv;
    const float* bias = (sel == 0) ? bq : (sel == 1) ? bk : bv;
    const float oscale = (sel == 0) ? qscale : 1.0f;
    const int K = D_, N = D_;

    const int mA = tid >> 2, g = tid & 3;
    const int gc = g ^ ((mA >> 2) & 3);
    const ushort* pa0 = A  + (size_t)(row0 + mA) * K + gc * 8;
    const ushort* pb0 = Bt + (size_t)(col0 + mA) * K + gc * 8;

    const int lane = tid & 63, w = tid >> 6;
    const int l15 = lane & 15, quad = lane >> 4;
    const int wm = w & 1, wn = w >> 1;
    const int csel = quad ^ ((l15 >> 2) & 3);
    int aoff[4], boff[4];
#pragma unroll
    for (int mt = 0; mt < 4; mt++) aoff[mt] = (wm * 64 + mt * 16 + l15) * 4 + csel;
#pragma unroll
    for (int nt = 0; nt < 4; nt++) boff[nt] = (wn * 64 + nt * 16 + l15) * 4 + csel;

    f32x4 acc[4][4] = {};

    const int kIter = K >> 5;
    for (int kt = 0; kt < kIter; ++kt) {
        if (kt) __syncthreads();
        glds16(pa0 + kt * 32,                     sA + tid);
        glds16(pa0 + kt * 32 + (size_t)64 * K,    sA + tid + 256);
        glds16(pb0 + kt * 32,                     sB + tid);
        glds16(pb0 + kt * 32 + (size_t)64 * K,    sB + tid + 256);
        __syncthreads();
        short8 af[4], bfr[4];
#pragma unroll
        for (int mt = 0; mt < 4; mt++) af[mt]  = __builtin_bit_cast(short8, sA[aoff[mt]]);
#pragma unroll
        for (int nt = 0; nt < 4; nt++) bfr[nt] = __builtin_bit_cast(short8, sB[boff[nt]]);
#pragma unroll
        for (int mt = 0; mt < 4; mt++)
#pragma unroll
            for (int nt = 0; nt < 4; nt++)
                acc[mt][nt] = __builtin_amdgcn_mfma_f32_16x16x32_bf16(af[mt], bfr[nt], acc[mt][nt], 0, 0, 0);
    }

    if (sel < 2) {
        ushort* Cout = (sel == 0) ? Qb : Kb;
#pragma unroll
        for (int nt = 0; nt < 4; nt++) {
            int col = col0 + wn * 64 + nt * 16 + l15;
            float bb = bias[col];
#pragma unroll
            for (int mt = 0; mt < 4; mt++) {
                int rowb = row0 + wm * 64 + mt * 16 + quad * 4;
#pragma unroll
                for (int r = 0; r < 4; ++r)
                    Cout[(size_t)(rowb + r) * N + col] = f2bf((acc[mt][nt][r] + bb) * oscale);
            }
        }
    } else {
        // V path: transpose 128x128 tile through LDS, emit f16 [B,H,DH,T]
        __syncthreads();
        ushort* tr = (ushort*)smem;        // [128 dh][136]
#pragma unroll
        for (int nt = 0; nt < 4; nt++) {
            int cl = wn * 64 + nt * 16 + l15;
            float bb = bias[col0 + cl];
#pragma unroll
            for (int mt = 0; mt < 4; mt++) {
                int rl = wm * 64 + mt * 16 + quad * 4;
#pragma unroll
                for (int r = 0; r < 4; ++r)
                    tr[cl * 136 + rl + r] = f2h(acc[mt][nt][r] + bb);
            }
        }
        __syncthreads();
        int b = row0 >> 11, t0 = row0 & (T_ - 1), h = col0 >> 7;
        for (int idx = tid; idx < 2048; idx += 256) {
            int dh = idx >> 4, c = idx & 15;
            uint4 v = *(const uint4*)(tr + dh * 136 + c * 8);
            *(uint4*)(Vtb + (size_t)((b * H_ + h) * DH_ + dh) * T_ + t0 + c * 8) = v;
        }
    }
}

// ---------------------------------------------------------------- O-projection GEMM (f32 out)
// launch_bounds(256,4): 60 arch + 64 AGPR = 124 <= 128-reg cap -> 4 blocks/CU,
// 1024 blocks = exactly 1 occupancy round.
__global__ __launch_bounds__(256, 4) void gemm_bt_f32(
    const ushort* __restrict__ A, const ushort* __restrict__ Bt,
    const float* __restrict__ bias, float* __restrict__ Cout,
    int M, int N, int K)
{
    extern __shared__ char smem[];
    uint4* sA = (uint4*)smem;
    uint4* sB = (uint4*)(smem + 8192);

    const int tid  = threadIdx.x;
    const int row0 = blockIdx.y * 128, col0 = blockIdx.x * 128;

    const int mA = tid >> 2, g = tid & 3;
    const int gc = g ^ ((mA >> 2) & 3);
    const ushort* pa0 = A  + (size_t)(row0 + mA) * K + gc * 8;
    const ushort* pb0 = Bt + (size_t)(col0 + mA) * K + gc * 8;

    const int lane = tid & 63, w = tid >> 6;
    const int l15 = lane & 15, quad = lane >> 4;
    const int wm = w & 1, wn = w >> 1;
    const int csel = quad ^ ((l15 >> 2) & 3);
    int aoff[4], boff[4];
#pragma unroll
    for (int mt = 0; mt < 4; mt++) aoff[mt] = (wm * 64 + mt * 16 + l15) * 4 + csel;
#pragma unroll
    for (int nt = 0; nt < 4; nt++) boff[nt] = (wn * 64 + nt * 16 + l15) * 4 + csel;

    f32x4 acc[4][4] = {};

    const int kIter = K >> 5;
    for (int kt = 0; kt < kIter; ++kt) {
        if (kt) __syncthreads();
        glds16(pa0 + kt * 32,                     sA + tid);
        glds16(pa0 + kt * 32 + (size_t)64 * K,    sA + tid + 256);
        glds16(pb0 + kt * 32,                     sB + tid);
        glds16(pb0 + kt * 32 + (size_t)64 * K,    sB + tid + 256);
        __syncthreads();
        short8 af[4], bfr[4];
#pragma unroll
        for (int mt = 0; mt < 4; mt++) af[mt]  = __builtin_bit_cast(short8, sA[aoff[mt]]);
#pragma unroll
        for (int nt = 0; nt < 4; nt++) bfr[nt] = __builtin_bit_cast(short8, sB[boff[nt]]);
#pragma unroll
        for (int mt = 0; mt < 4; mt++)
#pragma unroll
            for (int nt = 0; nt < 4; nt++)
                acc[mt][nt] = __builtin_amdgcn_mfma_f32_16x16x32_bf16(af[mt], bfr[nt], acc[mt][nt], 0, 0, 0);
    }

#pragma unroll
    for (int nt = 0; nt < 4; nt++) {
        int col = col0 + wn * 64 + nt * 16 + l15;
        float bb = bias[col];
#pragma unroll
        for (int mt = 0; mt < 4; mt++) {
            int rowb = row0 + wm * 64 + mt * 16 + quad * 4;
#pragma unroll
            for (int r = 0; r < 4; ++r)
                Cout[(size_t)(rowb + r) * N + col] = acc[mt][nt][r] + bb;
        }
    }
}

// ---------------------------------------------------------------- flash attention (S^T / O^T form)
// Q (pre-scaled by 1/sqrt(DH)*log2e), K: [B,T,D] bf16 ; Vt: [B,H,DH,T] f16 ; O: [B,T,D] bf16
// R8: ONE q-tile per block (2048 blocks), tile body byte-identical to the proven R0 kernel.
// Occupancy: (256,5) + 32 KiB LDS + ~80 regs -> 5 blocks/CU resident (was capped at 4 by
// the 1024-block grid; occupancy measured 38.7%). Mapping: xcd = bid&7; per XCD 8 heads
// co-resident (K/V 8 x 512KB = 4MB = L2); qt descending so long blocks dispatch first.
__global__ __launch_bounds__(256, 5) void attn_kernel(
    const ushort* __restrict__ Q, const ushort* __restrict__ K,
    const ushort* __restrict__ Vt, ushort* __restrict__ O)
{
    __shared__ __align__(16) char smem[32768];
    uint4*  kS = (uint4*)smem;                 // [64 s][16 chunks], chunk-swizzled
    ushort* vS = (ushort*)(smem + 16384);      // [128 dh][16 slots x 4 halfs], slot ^ (dh&15)

    const int tid = threadIdx.x;
    const int bid = blockIdx.x;                // 0..2047
    const int r  = bid >> 3;                   // 0..255
    const int g  = (bid & 7) + 8 * (r & 7);    // head-group 0..63 ; xcd = bid&7
    const int qt = 31 - (r >> 3);              // 31..0: long blocks first
    const int b = g >> 4, h = g & 15;

    const int lane = tid & 63, w = tid >> 6, l15 = lane & 15, quad = lane >> 4;

    const int krow = tid >> 4;                       // 0..15
    const int kchunk = (tid & 15) ^ (krow & 7);
    const ushort* kg = K + ((size_t)(b * T_) + krow) * D_ + h * DH_ + kchunk * 8;

    const int vrow = tid >> 3, vc = tid & 7;         // vrow 0..31, chunk 0..7 (8 halfs)
    const ushort* vg = Vt + ((size_t)((b * H_ + h) * DH_) + vrow) * T_ + vc * 8;
    const int vs0 = ((2 * vc    ) ^ (vrow & 15)) * 4;
    const int vs1 = ((2 * vc + 1) ^ (vrow & 15)) * 4;

    const int q0 = qt * 64;
    const int qbase = q0 + w * 16;               // wave's first q

    short8 aq[4];
    {
        const ushort* qp = Q + ((size_t)(b * T_) + qbase + l15) * D_ + h * DH_ + quad * 8;
#pragma unroll
        for (int ks = 0; ks < 4; ++ks)
            aq[ks] = __builtin_bit_cast(short8, *(const uint4*)(qp + ks * 32));
    }

    f32x4 accO[8] = {};                          // O^T[dh=nt*16+quad*4+r][q=l15]
    float mrow = -INFINITY, lrow = 0.f;

    auto tile = [&](int s0, int stMax, bool diag) {
        __syncthreads();                          // prior tile's readers done
        const ushort* kp = kg + (size_t)s0 * D_;
#pragma unroll
        for (int j = 0; j < 4; ++j) glds16(kp + (size_t)j * 16 * D_, kS + j * 256 + tid);
        const ushort* vp = vg + s0;
        uint4 vv[4];
#pragma unroll
        for (int j = 0; j < 4; ++j) vv[j] = *(const uint4*)(vp + (size_t)j * 32 * T_);
#pragma unroll
        for (int j = 0; j < 4; ++j) {
            ushort* dst = vS + (j * 32 + vrow) * 64;
            *(uint2*)(dst + vs0) = make_uint2(vv[j].x, vv[j].y);
            *(uint2*)(dst + vs1) = make_uint2(vv[j].z, vv[j].w);
        }
        __syncthreads();                          // tile ready

        f32x4 sT[4] = {};
#pragma unroll
        for (int ks = 0; ks < 4; ++ks)
#pragma unroll
            for (int st = 0; st < 4; ++st)
                if (st < stMax) {
                    int row = st * 16 + l15;
                    short8 ak = __builtin_bit_cast(short8, kS[row * 16 + ((ks * 4 + quad) ^ (row & 7))]);
                    sT[st] = __builtin_amdgcn_mfma_f32_16x16x32_bf16(ak, aq[ks], sT[st], 0, 0, 0);
                }

        if (diag) {
            const int q = qbase + l15;
            const int st = stMax - 1;
#pragma unroll
            for (int r2 = 0; r2 < 4; ++r2)
                if (s0 + st * 16 + quad * 4 + r2 > q) sT[st][r2] = -INFINITY;
        }

        float rmax = -INFINITY;
#pragma unroll
        for (int st = 0; st < 4; ++st)
            if (st < stMax)
#pragma unroll
                for (int r2 = 0; r2 < 4; ++r2) rmax = fmaxf(rmax, sT[st][r2]);
        rmax = fmaxf(rmax, __shfl_xor(rmax, 16));
        rmax = fmaxf(rmax, __shfl_xor(rmax, 32));
        float mnew  = fmaxf(mrow, rmax);
        float alpha = __builtin_amdgcn_exp2f(mrow - mnew);
        mrow = mnew;

        float psum = 0.f;
        half4 pb[4];
#pragma unroll
        for (int st = 0; st < 4; ++st)
            if (st < stMax) {
                float p0 = __builtin_amdgcn_exp2f(sT[st][0] - mnew);
                float p1 = __builtin_amdgcn_exp2f(sT[st][1] - mnew);
                float p2 = __builtin_amdgcn_exp2f(sT[st][2] - mnew);
                float p3 = __builtin_amdgcn_exp2f(sT[st][3] - mnew);
                psum += (p0 + p1) + (p2 + p3);
                uint2 u;
                u.x = __builtin_bit_cast(unsigned int, __builtin_amdgcn_cvt_pkrtz(p0, p1));
                u.y = __builtin_bit_cast(unsigned int, __builtin_amdgcn_cvt_pkrtz(p2, p3));
                pb[st] = __builtin_bit_cast(half4, u);
            }
        psum += __shfl_xor(psum, 16);
        psum += __shfl_xor(psum, 32);
        lrow = lrow * alpha + psum;
#pragma unroll
        for (int nt = 0; nt < 8; ++nt)
#pragma unroll
            for (int r2 = 0; r2 < 4; ++r2) accO[nt][r2] *= alpha;

#pragma unroll
        for (int st = 0; st < 4; ++st)
            if (st < stMax) {
#pragma unroll
                for (int nt = 0; nt < 8; ++nt) {
                    int dh = nt * 16 + l15;
                    half4 vf = *(const half4*)(vS + dh * 64 + (((st * 4 + quad) ^ l15) * 4));
                    accO[nt] = __builtin_amdgcn_mfma_f32_16x16x16f16(vf, pb[st], accO[nt], 0, 0, 0);
                }
            }
    };

    for (int it = 0; it < qt; ++it) tile(it * 64, 4, false);
    tile(qt * 64, w + 1, true);

    // epilogue: transpose O^T -> O via wave-private LDS, write bf16
    __syncthreads();                              // all waves done reading kS/vS
    ushort* eT = (ushort*)smem + w * 2176;        // [16 q][136 dh-pad]
    float inv = 1.0f / lrow;
#pragma unroll
    for (int nt = 0; nt < 8; ++nt) {
        int dh = nt * 16 + quad * 4;
#pragma unroll
        for (int r2 = 0; r2 < 4; ++r2)
            eT[l15 * 136 + dh + r2] = f2bf(accO[nt][r2] * inv);
    }
    for (int idx = lane; idx < 256; idx += 64) {
        int row = idx >> 4, c = idx & 15;
        uint4 v = *(const uint4*)(eT + row * 136 + c * 8);
        *(uint4*)(O + ((size_t)(b * T_) + q0 + w * 16 + row) * D_ + h * DH_ + c * 8) = v;
    }
}

extern "C" void kernel_launch(void* const* d_in, const int* in_sizes, int n_in,
                              void* d_out, int out_size, void* d_ws, size_t ws_size,
                              hipStream_t stream) {
    const float* x  = (const float*)d_in[0];
    const float* Wq = (const float*)d_in[1];
    const float* bq = (const float*)d_in[2];
    const float* Wk = (const float*)d_in[3];
    const float* bk = (const float*)d_in[4];
    const float* Wv = (const float*)d_in[5];
    const float* bv = (const float*)d_in[6];
    const float* Wo = (const float*)d_in[7];
    const float* bo = (const float*)d_in[8];

    char* ws = (char*)d_ws;
    const size_t MB = 1u << 20;
    ushort* xb  = (ushort*)(ws);
    ushort* Wqt = (ushort*)(ws + 32 * MB);
    ushort* Wkt = (ushort*)(ws + 40 * MB);
    ushort* Wvt = (ushort*)(ws + 48 * MB);
    ushort* Wot = (ushort*)(ws + 56 * MB);
    ushort* Qb  = (ushort*)(ws + 64 * MB);
    ushort* Kb  = (ushort*)(ws + 96 * MB);
    ushort* Vtb = (ushort*)(ws + 128 * MB);
    ushort* Ob  = (ushort*)(ws + 160 * MB);

    const int M = B_ * T_;   // 8192
    const float qscale = (float)(0.08838834764831845 * 1.4426950408889634); // 1/sqrt(DH) * log2(e)

    dim3 tb(32, 8), tg(D_ / 32, D_ / 32, 5);
    prep_kernel<<<tg, tb, 0, stream>>>(x, xb, Wq, Wk, Wv, Wo, Wqt, Wkt, Wvt, Wot);

    gemm_qkv<<<dim3(48, M / 128), 256, 34816, stream>>>(
        xb, Wqt, Wkt, Wvt, bq, bk, bv, Qb, Kb, Vtb, qscale);

    attn_kernel<<<dim3(2048), 256, 0, stream>>>(Qb, Kb, Vtb, Ob);

    gemm_bt_f32<<<dim3(D_ / 128, M / 128), 256, 16384, stream>>>(
        Ob, Wot, bo, (float*)d_out, M, D_, D_);
}

// Round 10
// 606.796 us; speedup vs baseline: 7.0718x; 1.0010x over previous
//
#include <hip/hip_runtime.h>
#include <hip/hip_bf16.h>

#define B_  4
#define T_  2048
#define D_  2048
#define H_  16
#define DH_ 128

typedef __attribute__((ext_vector_type(4))) float f32x4;
typedef __attribute__((ext_vector_type(8))) short short8;
typedef __attribute__((ext_vector_type(4))) _Float16 half4;

__device__ __forceinline__ ushort f2bf(float f) {
    unsigned int u = __builtin_bit_cast(unsigned int, f);
    u += 0x7fffu + ((u >> 16) & 1u);   // RNE
    return (ushort)(u >> 16);
}
__device__ __forceinline__ ushort f2h(float f) {
    return (ushort)(__builtin_bit_cast(unsigned int, __builtin_amdgcn_cvt_pkrtz(f, f)) & 0xffffu);
}

// async global -> LDS, 16B per lane. LDS dst must be wave-uniform base + lane*16.
__device__ __forceinline__ void glds16(const void* g, void* l) {
    __builtin_amdgcn_global_load_lds(
        (const __attribute__((address_space(1))) unsigned int*)g,
        (__attribute__((address_space(3))) unsigned int*)l, 16, 0, 0);
}

// ------------------------------------------------- fused prep: cast x->bf16 + 4x W transpose
__global__ void prep_kernel(
    const float* __restrict__ x, ushort* __restrict__ xb,
    const float* __restrict__ W0, const float* __restrict__ W1,
    const float* __restrict__ W2, const float* __restrict__ W3,
    ushort* __restrict__ T0, ushort* __restrict__ T1,
    ushort* __restrict__ T2, ushort* __restrict__ T3)
{
    __shared__ float tile[32][33];
    const int z = blockIdx.z;
    int tx = threadIdx.x, ty = threadIdx.y;           // 32 x 8
    if (z == 4) {
        int blk = blockIdx.y * 64 + blockIdx.x;
        int tid = ty * 32 + tx;
        size_t base = (size_t)blk * 4096 + tid * 4;
#pragma unroll
        for (int k2 = 0; k2 < 4; ++k2) {
            float4 v = *(const float4*)(x + base + k2 * 1024);
            ushort4 o;
            o.x = f2bf(v.x); o.y = f2bf(v.y); o.z = f2bf(v.z); o.w = f2bf(v.w);
            *(ushort4*)(xb + base + k2 * 1024) = o;
        }
        return;
    }
    const float* W = (z == 0) ? W0 : (z == 1) ? W1 : (z == 2) ? W2 : W3;
    ushort* Wt     = (z == 0) ? T0 : (z == 1) ? T1 : (z == 2) ? T2 : T3;
    int n0 = blockIdx.x * 32, k0 = blockIdx.y * 32;
#pragma unroll
    for (int i = 0; i < 4; i++)
        tile[ty + i * 8][tx] = W[(size_t)(k0 + ty + i * 8) * D_ + n0 + tx];
    __syncthreads();
#pragma unroll
    for (int i = 0; i < 4; i++)
        Wt[(size_t)(n0 + ty + i * 8) * D_ + k0 + tx] = f2bf(tile[tx][ty + i * 8]);
}

// ---------------------------------------------------------------- merged QKV GEMM (128^2)
// R9: minimal 2-phase double-buffered K-loop (T3 recipe): per K-step, stage(kt+1 -> buf^1)
// is issued BEFORE ds_read+MFMA of buf, then ONE __syncthreads() (compiler emits
// vmcnt(0)+lgkmcnt(0) before s_barrier) per step. Staging latency hides under own MFMAs;
// barriers/K-step 2 -> 1. LDS: 2 x (sA 8K + sB 8K) = 32 KB; dynamic 34816 (V-transpose).
// (256,4): 60 VGPR + 64 AGPR = 124 <= 128 cap (proven spill-free on gemm_bt R8);
// 3072 blocks = exactly 3 rounds of 1024 resident.
__global__ __launch_bounds__(256, 4) void gemm_qkv(
    const ushort* __restrict__ A,
    const ushort* __restrict__ Wq, const ushort* __restrict__ Wk, const ushort* __restrict__ Wv,
    const float* __restrict__ bq, const float* __restrict__ bk, const float* __restrict__ bv,
    ushort* __restrict__ Qb, ushort* __restrict__ Kb, ushort* __restrict__ Vtb,
    float qscale)
{
    extern __shared__ char smem[];

    const int tid  = threadIdx.x;
    const int sel  = blockIdx.x >> 4;           // 0=Q 1=K 2=V
    const int row0 = blockIdx.y * 128, col0 = (blockIdx.x & 15) * 128;
    const ushort* Bt = (sel == 0) ? Wq : (sel == 1) ? Wk : Wv;
    const float* bias = (sel == 0) ? bq : (sel == 1) ? bk : bv;
    const float oscale = (sel == 0) ? qscale : 1.0f;
    const int K = D_, N = D_;

    const int mA = tid >> 2, g = tid & 3;
    const int gc = g ^ ((mA >> 2) & 3);
    const ushort* pa0 = A  + (size_t)(row0 + mA) * K + gc * 8;
    const ushort* pb0 = Bt + (size_t)(col0 + mA) * K + gc * 8;

    const int lane = tid & 63, w = tid >> 6;
    const int l15 = lane & 15, quad = lane >> 4;
    const int wm = w & 1, wn = w >> 1;
    const int csel = quad ^ ((l15 >> 2) & 3);
    int aoff[4], boff[4];
#pragma unroll
    for (int mt = 0; mt < 4; mt++) aoff[mt] = (wm * 64 + mt * 16 + l15) * 4 + csel;
#pragma unroll
    for (int nt = 0; nt < 4; nt++) boff[nt] = (wn * 64 + nt * 16 + l15) * 4 + csel;

    f32x4 acc[4][4] = {};

    // prologue: stage kt=0 into buf0
    {
        char* b0 = smem + tid * 16;
        glds16(pa0,                    b0);
        glds16(pa0 + (size_t)64 * K,   b0 + 4096);
        glds16(pb0,                    b0 + 8192);
        glds16(pb0 + (size_t)64 * K,   b0 + 12288);
    }
    __syncthreads();

    const int kIter = K >> 5;
    for (int kt = 0; kt < kIter; ++kt) {
        if (kt + 1 < kIter) {               // stage kt+1 into buf^1 BEFORE compute
            char* nx = smem + (((kt + 1) & 1) << 14) + tid * 16;
            glds16(pa0 + (kt + 1) * 32,                    nx);
            glds16(pa0 + (kt + 1) * 32 + (size_t)64 * K,   nx + 4096);
            glds16(pb0 + (kt + 1) * 32,                    nx + 8192);
            glds16(pb0 + (kt + 1) * 32 + (size_t)64 * K,   nx + 12288);
        }
        const uint4* sA = (const uint4*)(smem + ((kt & 1) << 14));
        const uint4* sB = (const uint4*)(smem + ((kt & 1) << 14) + 8192);
        short8 af[4], bfr[4];
#pragma unroll
        for (int mt = 0; mt < 4; mt++) af[mt]  = __builtin_bit_cast(short8, sA[aoff[mt]]);
#pragma unroll
        for (int nt = 0; nt < 4; nt++) bfr[nt] = __builtin_bit_cast(short8, sB[boff[nt]]);
#pragma unroll
        for (int mt = 0; mt < 4; mt++)
#pragma unroll
            for (int nt = 0; nt < 4; nt++)
                acc[mt][nt] = __builtin_amdgcn_mfma_f32_16x16x32_bf16(af[mt], bfr[nt], acc[mt][nt], 0, 0, 0);
        __syncthreads();                    // drains vmcnt (stages landed) + lgkm; WAR-safe
    }

    if (sel < 2) {
        ushort* Cout = (sel == 0) ? Qb : Kb;
#pragma unroll
        for (int nt = 0; nt < 4; nt++) {
            int col = col0 + wn * 64 + nt * 16 + l15;
            float bb = bias[col];
#pragma unroll
            for (int mt = 0; mt < 4; mt++) {
                int rowb = row0 + wm * 64 + mt * 16 + quad * 4;
#pragma unroll
                for (int r = 0; r < 4; ++r)
                    Cout[(size_t)(rowb + r) * N + col] = f2bf((acc[mt][nt][r] + bb) * oscale);
            }
        }
    } else {
        // V path: transpose 128x128 tile through LDS, emit f16 [B,H,DH,T]
        ushort* tr = (ushort*)smem;        // [128 dh][136]
#pragma unroll
        for (int nt = 0; nt < 4; nt++) {
            int cl = wn * 64 + nt * 16 + l15;
            float bb = bias[col0 + cl];
#pragma unroll
            for (int mt = 0; mt < 4; mt++) {
                int rl = wm * 64 + mt * 16 + quad * 4;
#pragma unroll
                for (int r = 0; r < 4; ++r)
                    tr[cl * 136 + rl + r] = f2h(acc[mt][nt][r] + bb);
            }
        }
        __syncthreads();
        int b = row0 >> 11, t0 = row0 & (T_ - 1), h = col0 >> 7;
        for (int idx = tid; idx < 2048; idx += 256) {
            int dh = idx >> 4, c = idx & 15;
            uint4 v = *(const uint4*)(tr + dh * 136 + c * 8);
            *(uint4*)(Vtb + (size_t)((b * H_ + h) * DH_ + dh) * T_ + t0 + c * 8) = v;
        }
    }
}

// ---------------------------------------------------------------- O-projection GEMM (f32 out)
// R9: same 2-phase dbuf K-loop. LDS 32 KB x 4 blocks/CU = 128 KB.
__global__ __launch_bounds__(256, 4) void gemm_bt_f32(
    const ushort* __restrict__ A, const ushort* __restrict__ Bt,
    const float* __restrict__ bias, float* __restrict__ Cout,
    int M, int N, int K)
{
    extern __shared__ char smem[];

    const int tid  = threadIdx.x;
    const int row0 = blockIdx.y * 128, col0 = blockIdx.x * 128;

    const int mA = tid >> 2, g = tid & 3;
    const int gc = g ^ ((mA >> 2) & 3);
    const ushort* pa0 = A  + (size_t)(row0 + mA) * K + gc * 8;
    const ushort* pb0 = Bt + (size_t)(col0 + mA) * K + gc * 8;

    const int lane = tid & 63, w = tid >> 6;
    const int l15 = lane & 15, quad = lane >> 4;
    const int wm = w & 1, wn = w >> 1;
    const int csel = quad ^ ((l15 >> 2) & 3);
    int aoff[4], boff[4];
#pragma unroll
    for (int mt = 0; mt < 4; mt++) aoff[mt] = (wm * 64 + mt * 16 + l15) * 4 + csel;
#pragma unroll
    for (int nt = 0; nt < 4; nt++) boff[nt] = (wn * 64 + nt * 16 + l15) * 4 + csel;

    f32x4 acc[4][4] = {};

    {
        char* b0 = smem + tid * 16;
        glds16(pa0,                    b0);
        glds16(pa0 + (size_t)64 * K,   b0 + 4096);
        glds16(pb0,                    b0 + 8192);
        glds16(pb0 + (size_t)64 * K,   b0 + 12288);
    }
    __syncthreads();

    const int kIter = K >> 5;
    for (int kt = 0; kt < kIter; ++kt) {
        if (kt + 1 < kIter) {
            char* nx = smem + (((kt + 1) & 1) << 14) + tid * 16;
            glds16(pa0 + (kt + 1) * 32,                    nx);
            glds16(pa0 + (kt + 1) * 32 + (size_t)64 * K,   nx + 4096);
            glds16(pb0 + (kt + 1) * 32,                    nx + 8192);
            glds16(pb0 + (kt + 1) * 32 + (size_t)64 * K,   nx + 12288);
        }
        const uint4* sA = (const uint4*)(smem + ((kt & 1) << 14));
        const uint4* sB = (const uint4*)(smem + ((kt & 1) << 14) + 8192);
        short8 af[4], bfr[4];
#pragma unroll
        for (int mt = 0; mt < 4; mt++) af[mt]  = __builtin_bit_cast(short8, sA[aoff[mt]]);
#pragma unroll
        for (int nt = 0; nt < 4; nt++) bfr[nt] = __builtin_bit_cast(short8, sB[boff[nt]]);
#pragma unroll
        for (int mt = 0; mt < 4; mt++)
#pragma unroll
            for (int nt = 0; nt < 4; nt++)
                acc[mt][nt] = __builtin_amdgcn_mfma_f32_16x16x32_bf16(af[mt], bfr[nt], acc[mt][nt], 0, 0, 0);
        __syncthreads();
    }

#pragma unroll
    for (int nt = 0; nt < 4; nt++) {
        int col = col0 + wn * 64 + nt * 16 + l15;
        float bb = bias[col];
#pragma unroll
        for (int mt = 0; mt < 4; mt++) {
            int rowb = row0 + wm * 64 + mt * 16 + quad * 4;
#pragma unroll
            for (int r = 0; r < 4; ++r)
                Cout[(size_t)(rowb + r) * N + col] = acc[mt][nt][r] + bb;
        }
    }
}

// ---------------------------------------------------------------- flash attention (S^T / O^T form)
// R8-proven: ONE q-tile per block (2048 blocks), 5 blocks/CU, tile body = R0 kernel.
__global__ __launch_bounds__(256, 5) void attn_kernel(
    const ushort* __restrict__ Q, const ushort* __restrict__ K,
    const ushort* __restrict__ Vt, ushort* __restrict__ O)
{
    __shared__ __align__(16) char smem[32768];
    uint4*  kS = (uint4*)smem;                 // [64 s][16 chunks], chunk-swizzled
    ushort* vS = (ushort*)(smem + 16384);      // [128 dh][16 slots x 4 halfs], slot ^ (dh&15)

    const int tid = threadIdx.x;
    const int bid = blockIdx.x;                // 0..2047
    const int r  = bid >> 3;                   // 0..255
    const int g  = (bid & 7) + 8 * (r & 7);    // head-group 0..63 ; xcd = bid&7
    const int qt = 31 - (r >> 3);              // 31..0: long blocks first
    const int b = g >> 4, h = g & 15;

    const int lane = tid & 63, w = tid >> 6, l15 = lane & 15, quad = lane >> 4;

    const int krow = tid >> 4;                       // 0..15
    const int kchunk = (tid & 15) ^ (krow & 7);
    const ushort* kg = K + ((size_t)(b * T_) + krow) * D_ + h * DH_ + kchunk * 8;

    const int vrow = tid >> 3, vc = tid & 7;         // vrow 0..31, chunk 0..7 (8 halfs)
    const ushort* vg = Vt + ((size_t)((b * H_ + h) * DH_) + vrow) * T_ + vc * 8;
    const int vs0 = ((2 * vc    ) ^ (vrow & 15)) * 4;
    const int vs1 = ((2 * vc + 1) ^ (vrow & 15)) * 4;

    const int q0 = qt * 64;
    const int qbase = q0 + w * 16;               // wave's first q

    short8 aq[4];
    {
        const ushort* qp = Q + ((size_t)(b * T_) + qbase + l15) * D_ + h * DH_ + quad * 8;
#pragma unroll
        for (int ks = 0; ks < 4; ++ks)
            aq[ks] = __builtin_bit_cast(short8, *(const uint4*)(qp + ks * 32));
    }

    f32x4 accO[8] = {};                          // O^T[dh=nt*16+quad*4+r][q=l15]
    float mrow = -INFINITY, lrow = 0.f;

    auto tile = [&](int s0, int stMax, bool diag) {
        __syncthreads();                          // prior tile's readers done
        const ushort* kp = kg + (size_t)s0 * D_;
#pragma unroll
        for (int j = 0; j < 4; ++j) glds16(kp + (size_t)j * 16 * D_, kS + j * 256 + tid);
        const ushort* vp = vg + s0;
        uint4 vv[4];
#pragma unroll
        for (int j = 0; j < 4; ++j) vv[j] = *(const uint4*)(vp + (size_t)j * 32 * T_);
#pragma unroll
        for (int j = 0; j < 4; ++j) {
            ushort* dst = vS + (j * 32 + vrow) * 64;
            *(uint2*)(dst + vs0) = make_uint2(vv[j].x, vv[j].y);
            *(uint2*)(dst + vs1) = make_uint2(vv[j].z, vv[j].w);
        }
        __syncthreads();                          // tile ready

        f32x4 sT[4] = {};
#pragma unroll
        for (int ks = 0; ks < 4; ++ks)
#pragma unroll
            for (int st = 0; st < 4; ++st)
                if (st < stMax) {
                    int row = st * 16 + l15;
                    short8 ak = __builtin_bit_cast(short8, kS[row * 16 + ((ks * 4 + quad) ^ (row & 7))]);
                    sT[st] = __builtin_amdgcn_mfma_f32_16x16x32_bf16(ak, aq[ks], sT[st], 0, 0, 0);
                }

        if (diag) {
            const int q = qbase + l15;
            const int st = stMax - 1;
#pragma unroll
            for (int r2 = 0; r2 < 4; ++r2)
                if (s0 + st * 16 + quad * 4 + r2 > q) sT[st][r2] = -INFINITY;
        }

        float rmax = -INFINITY;
#pragma unroll
        for (int st = 0; st < 4; ++st)
            if (st < stMax)
#pragma unroll
                for (int r2 = 0; r2 < 4; ++r2) rmax = fmaxf(rmax, sT[st][r2]);
        rmax = fmaxf(rmax, __shfl_xor(rmax, 16));
        rmax = fmaxf(rmax, __shfl_xor(rmax, 32));
        float mnew  = fmaxf(mrow, rmax);
        float alpha = __builtin_amdgcn_exp2f(mrow - mnew);
        mrow = mnew;

        float psum = 0.f;
        half4 pb[4];
#pragma unroll
        for (int st = 0; st < 4; ++st)
            if (st < stMax) {
                float p0 = __builtin_amdgcn_exp2f(sT[st][0] - mnew);
                float p1 = __builtin_amdgcn_exp2f(sT[st][1] - mnew);
                float p2 = __builtin_amdgcn_exp2f(sT[st][2] - mnew);
                float p3 = __builtin_amdgcn_exp2f(sT[st][3] - mnew);
                psum += (p0 + p1) + (p2 + p3);
                uint2 u;
                u.x = __builtin_bit_cast(unsigned int, __builtin_amdgcn_cvt_pkrtz(p0, p1));
                u.y = __builtin_bit_cast(unsigned int, __builtin_amdgcn_cvt_pkrtz(p2, p3));
                pb[st] = __builtin_bit_cast(half4, u);
            }
        psum += __shfl_xor(psum, 16);
        psum += __shfl_xor(psum, 32);
        lrow = lrow * alpha + psum;
#pragma unroll
        for (int nt = 0; nt < 8; ++nt)
#pragma unroll
            for (int r2 = 0; r2 < 4; ++r2) accO[nt][r2] *= alpha;

#pragma unroll
        for (int st = 0; st < 4; ++st)
            if (st < stMax) {
#pragma unroll
                for (int nt = 0; nt < 8; ++nt) {
                    int dh = nt * 16 + l15;
                    half4 vf = *(const half4*)(vS + dh * 64 + (((st * 4 + quad) ^ l15) * 4));
                    accO[nt] = __builtin_amdgcn_mfma_f32_16x16x16f16(vf, pb[st], accO[nt], 0, 0, 0);
                }
            }
    };

    for (int it = 0; it < qt; ++it) tile(it * 64, 4, false);
    tile(qt * 64, w + 1, true);

    // epilogue: transpose O^T -> O via wave-private LDS, write bf16
    __syncthreads();                              // all waves done reading kS/vS
    ushort* eT = (ushort*)smem + w * 2176;        // [16 q][136 dh-pad]
    float inv = 1.0f / lrow;
#pragma unroll
    for (int nt = 0; nt < 8; ++nt) {
        int dh = nt * 16 + quad * 4;
#pragma unroll
        for (int r2 = 0; r2 < 4; ++r2)
            eT[l15 * 136 + dh + r2] = f2bf(accO[nt][r2] * inv);
    }
    for (int idx = lane; idx < 256; idx += 64) {
        int row = idx >> 4, c = idx & 15;
        uint4 v = *(const uint4*)(eT + row * 136 + c * 8);
        *(uint4*)(O + ((size_t)(b * T_) + q0 + w * 16 + row) * D_ + h * DH_ + c * 8) = v;
    }
}

extern "C" void kernel_launch(void* const* d_in, const int* in_sizes, int n_in,
                              void* d_out, int out_size, void* d_ws, size_t ws_size,
                              hipStream_t stream) {
    const float* x  = (const float*)d_in[0];
    const float* Wq = (const float*)d_in[1];
    const float* bq = (const float*)d_in[2];
    const float* Wk = (const float*)d_in[3];
    const float* bk = (const float*)d_in[4];
    const float* Wv = (const float*)d_in[5];
    const float* bv = (const float*)d_in[6];
    const float* Wo = (const float*)d_in[7];
    const float* bo = (const float*)d_in[8];

    char* ws = (char*)d_ws;
    const size_t MB = 1u << 20;
    ushort* xb  = (ushort*)(ws);
    ushort* Wqt = (ushort*)(ws + 32 * MB);
    ushort* Wkt = (ushort*)(ws + 40 * MB);
    ushort* Wvt = (ushort*)(ws + 48 * MB);
    ushort* Wot = (ushort*)(ws + 56 * MB);
    ushort* Qb  = (ushort*)(ws + 64 * MB);
    ushort* Kb  = (ushort*)(ws + 96 * MB);
    ushort* Vtb = (ushort*)(ws + 128 * MB);
    ushort* Ob  = (ushort*)(ws + 160 * MB);

    const int M = B_ * T_;   // 8192
    const float qscale = (float)(0.08838834764831845 * 1.4426950408889634); // 1/sqrt(DH) * log2(e)

    dim3 tb(32, 8), tg(D_ / 32, D_ / 32, 5);
    prep_kernel<<<tg, tb, 0, stream>>>(x, xb, Wq, Wk, Wv, Wo, Wqt, Wkt, Wvt, Wot);

    gemm_qkv<<<dim3(48, M / 128), 256, 34816, stream>>>(
        xb, Wqt, Wkt, Wvt, bq, bk, bv, Qb, Kb, Vtb, qscale);

    attn_kernel<<<dim3(2048), 256, 0, stream>>>(Qb, Kb, Vtb, Ob);

    gemm_bt_f32<<<dim3(D_ / 128, M / 128), 256, 32768, stream>>>(
        Ob, Wot, bo, (float*)d_out, M, D_, D_);
}